// Round 12
// baseline (244.423 us; speedup 1.0000x reference)
//
#include <hip/hip_runtime.h>

// ---------------------------------------------------------------------------
// Fused GQA attention: B=2, L=2048, D=1024, H=16, G=2, HPG=8, DQK=DV=128.
// Inputs fp32, OUTPUT fp32. bf16 MFMA compute, fp32 accumulation.
//
// attn: 32x32x16 MFMA, in-register P (T12), T15 QK||SM pipeline, 64 KB LDS,
// launch_bounds(256,2) -- round-7 winner, UNCHANGED (round-8: 3 waves/EU
// spills accumulators; never raise occupancy without cutting regs).
//
// ROUND-11: fuse the fp32->bf16 input cvt into proj_qkv A-staging (T14
// reg-staged split: load f32 early, cvt+ds_write late, hidden under MFMAs).
// prep drops its 6144 cvt blocks (~72 MB HBM round-trip) -> 4608 transpose-
// only blocks. proj_o / attn byte-identical to the measured round-10 state.
// ---------------------------------------------------------------------------

typedef __bf16 bf16;
typedef __bf16 bf16x8 __attribute__((ext_vector_type(8)));
typedef __bf16 bf16x4 __attribute__((ext_vector_type(4)));
typedef float f32x4 __attribute__((ext_vector_type(4)));
typedef float f32x16 __attribute__((ext_vector_type(16)));
typedef float float4v __attribute__((ext_vector_type(4)));

#define MFMA_BF16(a, b, c) __builtin_amdgcn_mfma_f32_16x16x32_bf16((a), (b), (c), 0, 0, 0)
#define MFMA32(a, b, c)    __builtin_amdgcn_mfma_f32_32x32x16_bf16((a), (b), (c), 0, 0, 0)

static constexpr int Bz = 2, Lz = 2048, Dz = 1024;
static constexpr int Hz = 16, Gz = 2;
static constexpr int DQKz = 128, DVz = 128;

__device__ __forceinline__ void async_copy16(const bf16* g, bf16* l) {
    __builtin_amdgcn_global_load_lds(
        (const __attribute__((address_space(1))) unsigned int*)g,
        (__attribute__((address_space(3))) unsigned int*)l, 16, 0, 0);
}

__device__ __forceinline__ unsigned cvt_pk_bf16(float lo, float hi) {
    unsigned r;
    asm("v_cvt_pk_bf16_f32 %0, %1, %2" : "=v"(r) : "v"(lo), "v"(hi));
    return r;
}

__device__ __forceinline__ bf16x8 cvt8(float4v a, float4v b) {
    bf16x8 o;
    #pragma unroll
    for (int j = 0; j < 4; ++j) { o[j] = (bf16)a[j]; o[j + 4] = (bf16)b[j]; }
    return o;
}

// ---------------- prep: weight transposes only ------------------------------
// grid: 4608 blocks x 256 thr; 32x32 tiles: Wq 2048, Wk 256, Wv 256, Wo 2048
__global__ __launch_bounds__(256) void prep(
    const float* __restrict__ Wq, const float* __restrict__ Wk,
    const float* __restrict__ Wv, const float* __restrict__ Wo,
    bf16* __restrict__ WqT, bf16* __restrict__ WkT,
    bf16* __restrict__ WvT, bf16* __restrict__ WoT)
{
    int bid = blockIdx.x;
    const float* W; bf16* WT; int K, N;
    if (bid < 2048)      { W = Wq; WT = WqT; K = 1024; N = 2048; }
    else if (bid < 2304) { W = Wk; WT = WkT; K = 1024; N = 256;  bid -= 2048; }
    else if (bid < 2560) { W = Wv; WT = WvT; K = 1024; N = 256;  bid -= 2304; }
    else                 { W = Wo; WT = WoT; K = 2048; N = 1024; bid -= 2560; }
    int tiles_n = N >> 5;
    int n0 = (bid % tiles_n) * 32, k0 = (bid / tiles_n) * 32;

    __shared__ bf16 t[32][33];
    int tx = threadIdx.x & 31, ty = threadIdx.x >> 5;
    #pragma unroll
    for (int i = 0; i < 4; ++i)
        t[ty + i * 8][tx] = (bf16)W[(size_t)(k0 + ty + i * 8) * N + n0 + tx];
    __syncthreads();
    #pragma unroll
    for (int i = 0; i < 4; ++i)
        WT[(size_t)(n0 + ty + i * 8) * K + k0 + tx] = t[tx][ty + i * 8];
}

// ---------------- pipelined GEMM body: 128x128 tile, BK64, 512 thr ----------
// 8 waves as 2(m) x 4(n); wave-tile 64x32. Double-buffered LDS, single
// barrier per k-iter. F32A: A is fp32, reg-staged (load early, cvt+ds_write
// after the MFMA block -- T14 split; barrier drains vmcnt+lgkmcnt).
template <typename TC, typename TA>
__device__ __forceinline__ void gemm_tile(
    const TA* __restrict__ A, const bf16* __restrict__ BT,
    const float* __restrict__ bias, float scale, TC* __restrict__ C,
    int M, int N, int K, int m0, int n0, bool trans_out,
    bf16 (&As)[2][128 * 64], bf16 (&Bs)[2][128 * 64])
{
    constexpr bool F32A = sizeof(TA) == 4;
    const int tid  = threadIdx.x;        // 512
    const int wave = tid >> 6;
    const int lane = tid & 63;
    const int quad = lane >> 4;
    const int l16  = lane & 15;
    const int sw   = l16 & 7;
    const int wm = wave >> 2, wn = wave & 3;

    f32x4 acc[4][2] = {};

    auto stageA_async = [&](int k0, int buf) {   // TA == bf16 path
        #pragma unroll
        for (int s = 0; s < 2; ++s) {
            int i = s * 512 + tid;
            int row = i >> 3, c = (i & 7) ^ (row & 7);
            async_copy16((const bf16*)A + (size_t)(m0 + row) * K + k0 + c * 8,
                         &As[buf][i * 8]);
        }
    };
    auto loadA = [&](int k0, float4v (&ra)[2][2]) {  // TA == float path
        #pragma unroll
        for (int s = 0; s < 2; ++s) {
            int i = s * 512 + tid;
            int row = i >> 3, c = (i & 7) ^ (row & 7);
            const float* src = (const float*)A + (size_t)(m0 + row) * K + k0 + c * 8;
            ra[s][0] = *(const float4v*)src;
            ra[s][1] = *(const float4v*)(src + 4);
        }
    };
    auto writeA = [&](int buf, float4v (&ra)[2][2]) {
        #pragma unroll
        for (int s = 0; s < 2; ++s) {
            int i = s * 512 + tid;
            *(bf16x8*)(&As[buf][i * 8]) = cvt8(ra[s][0], ra[s][1]);
        }
    };
    auto stageB = [&](int k0, int buf) {
        #pragma unroll
        for (int s = 0; s < 2; ++s) {
            int i = s * 512 + tid;
            int row = i >> 3, c = (i & 7) ^ (row & 7);
            async_copy16(BT + (size_t)(n0 + row) * K + k0 + c * 8, &Bs[buf][i * 8]);
        }
    };

    // prologue
    float4v ra[2][2];
    if constexpr (F32A) { loadA(0, ra); stageB(0, 0); writeA(0, ra); }
    else                { stageA_async(0, 0); stageB(0, 0); }

    int cur = 0;
    for (int k0 = 0; k0 < K; k0 += 64) {
        __syncthreads();                    // drains async loads + ds_writes
        const bool hav = (k0 + 64 < K);
        float4v rn[2][2];
        if (hav) {
            if constexpr (F32A) loadA(k0 + 64, rn);   // issue early (T14)
            else                stageA_async(k0 + 64, cur ^ 1);
            stageB(k0 + 64, cur ^ 1);
        }

        #pragma unroll
        for (int ks = 0; ks < 2; ++ks) {
            bf16x8 af[4], bfv[2];
            #pragma unroll
            for (int mt = 0; mt < 4; ++mt)
                af[mt] = *(const bf16x8*)(&As[cur][((wm * 64 + mt * 16 + l16) * 8
                                                    + ((ks * 4 + quad) ^ sw)) * 8]);
            #pragma unroll
            for (int nt = 0; nt < 2; ++nt)
                bfv[nt] = *(const bf16x8*)(&Bs[cur][((wn * 32 + nt * 16 + l16) * 8
                                                     + ((ks * 4 + quad) ^ sw)) * 8]);
            #pragma unroll
            for (int mt = 0; mt < 4; ++mt)
                #pragma unroll
                for (int nt = 0; nt < 2; ++nt)
                    acc[mt][nt] = MFMA_BF16(af[mt], bfv[nt], acc[mt][nt]);
        }

        if constexpr (F32A) { if (hav) writeA(cur ^ 1, rn); }  // write late
        cur ^= 1;
    }

    #pragma unroll
    for (int nt = 0; nt < 2; ++nt) {
        int col = n0 + wn * 32 + nt * 16 + l16;
        float bv = bias[col];
        #pragma unroll
        for (int mt = 0; mt < 4; ++mt) {
            int row = m0 + wm * 64 + mt * 16 + quad * 4;
            if (trans_out) {
                struct V4 { TC v[4]; } o;
                #pragma unroll
                for (int r = 0; r < 4; ++r)
                    o.v[r] = (TC)((acc[mt][nt][r] + bv) * scale);
                *(V4*)(&C[(size_t)col * M + row]) = o;
            } else {
                #pragma unroll
                for (int r = 0; r < 4; ++r)
                    C[(size_t)(row + r) * N + col] =
                        (TC)((acc[mt][nt][r] + bv) * scale);
            }
        }
    }
}

// ---------------- GEMM body 64x128 tile, BK64, 512 thr ----------------------
// 8 waves as 2(m) x 4(n); wave-tile 32x32 (acc[2][2]). As = 2x64x64,
// Bs = 2x128x64 (raw pointers; may alias a larger allocation).
template <typename TC, bool TRANS, typename TA>
__device__ __forceinline__ void gemm_tile64(
    const TA* __restrict__ A, const bf16* __restrict__ BT,
    const float* __restrict__ bias, float scale, TC* __restrict__ C,
    int M, int N, int K, int m0, int n0, bf16* As, bf16* Bs)
{
    constexpr bool F32A = sizeof(TA) == 4;
    const int tid  = threadIdx.x;        // 512
    const int wave = tid >> 6;
    const int lane = tid & 63;
    const int quad = lane >> 4;
    const int l16  = lane & 15;
    const int sw   = l16 & 7;
    const int wm = wave >> 2, wn = wave & 3;   // 2m x 4n

    f32x4 acc[2][2] = {};

    auto stageA_async = [&](int k0, int buf) {
        int i = tid;                       // 64x64 = 512 x 16B, 1 round
        int row = i >> 3, c = (i & 7) ^ (row & 7);
        async_copy16((const bf16*)A + (size_t)(m0 + row) * K + k0 + c * 8,
                     As + buf * 4096 + i * 8);
    };
    auto loadA = [&](int k0, float4v (&ra)[2]) {
        int i = tid;
        int row = i >> 3, c = (i & 7) ^ (row & 7);
        const float* src = (const float*)A + (size_t)(m0 + row) * K + k0 + c * 8;
        ra[0] = *(const float4v*)src;
        ra[1] = *(const float4v*)(src + 4);
    };
    auto writeA = [&](int buf, float4v (&ra)[2]) {
        *(bf16x8*)(As + buf * 4096 + tid * 8) = cvt8(ra[0], ra[1]);
    };
    auto stageB = [&](int k0, int buf) {
        #pragma unroll
        for (int s = 0; s < 2; ++s) {          // 128x64 = 2 rounds
            int i = s * 512 + tid;
            int row = i >> 3, c = (i & 7) ^ (row & 7);
            async_copy16(BT + (size_t)(n0 + row) * K + k0 + c * 8,
                         Bs + buf * 8192 + i * 8);
        }
    };

    float4v ra[2];
    if constexpr (F32A) { loadA(0, ra); stageB(0, 0); writeA(0, ra); }
    else                { stageA_async(0, 0); stageB(0, 0); }

    int cur = 0;
    for (int k0 = 0; k0 < K; k0 += 64) {
        __syncthreads();                    // drains async loads + ds_writes
        const bool hav = (k0 + 64 < K);
        float4v rn[2];
        if (hav) {
            if constexpr (F32A) loadA(k0 + 64, rn);
            else                stageA_async(k0 + 64, cur ^ 1);
            stageB(k0 + 64, cur ^ 1);
        }

        #pragma unroll
        for (int ks = 0; ks < 2; ++ks) {
            bf16x8 af[2], bfv[2];
            #pragma unroll
            for (int mt = 0; mt < 2; ++mt)
                af[mt] = *(const bf16x8*)(As + cur * 4096
                           + ((wm * 32 + mt * 16 + l16) * 8
                              + ((ks * 4 + quad) ^ sw)) * 8);
            #pragma unroll
            for (int nt = 0; nt < 2; ++nt)
                bfv[nt] = *(const bf16x8*)(Bs + cur * 8192
                            + ((wn * 32 + nt * 16 + l16) * 8
                               + ((ks * 4 + quad) ^ sw)) * 8);
            #pragma unroll
            for (int mt = 0; mt < 2; ++mt)
                #pragma unroll
                for (int nt = 0; nt < 2; ++nt)
                    acc[mt][nt] = MFMA_BF16(af[mt], bfv[nt], acc[mt][nt]);
        }

        if constexpr (F32A) { if (hav) writeA(cur ^ 1, rn); }
        cur ^= 1;
    }

    #pragma unroll
    for (int nt = 0; nt < 2; ++nt) {
        int col = n0 + wn * 32 + nt * 16 + l16;
        float bv = bias[col];
        #pragma unroll
        for (int mt = 0; mt < 2; ++mt) {
            int row = m0 + wm * 32 + mt * 16 + quad * 4;
            if constexpr (TRANS) {
                struct V4 { TC v[4]; } o;
                #pragma unroll
                for (int r = 0; r < 4; ++r)
                    o.v[r] = (TC)((acc[mt][nt][r] + bv) * scale);
                *(V4*)(&C[(size_t)col * M + row]) = o;
            } else {
                #pragma unroll
                for (int r = 0; r < 4; ++r)
                    C[(size_t)(row + r) * N + col] =
                        (TC)((acc[mt][nt][r] + bv) * scale);
            }
        }
    }
}

// ---------------- Q+K+V projections (read fp32 inputs directly) -------------
// grid 768 = 3 blocks/CU uniform: [0,512) Q 128x128; [512,640) K 64x128;
// [640,768) V 64x128 transposed-out. A-cvt fused (no prep cvt pass).
__global__ __launch_bounds__(512, 4) void proj_qkv(
    const float* __restrict__ in_q, const float* __restrict__ in_k,
    const float* __restrict__ in_v, const bf16* __restrict__ WqT,
    const bf16* __restrict__ WkT, const bf16* __restrict__ WvT,
    const float* __restrict__ bq, const float* __restrict__ bk,
    const float* __restrict__ bv, const float* __restrict__ qsc,
    bf16* __restrict__ Qw, bf16* __restrict__ Kw, bf16* __restrict__ VwT)
{
    __shared__ bf16 As[2][128 * 64];
    __shared__ bf16 Bs[2][128 * 64];
    int bid = blockIdx.x;
    if (bid < 512) {
        // scale = qsc / sqrt(128) * log2(e)  (exp2-domain softmax)
        float scale = qsc[0] * 0.08838834764831845f * 1.4426950408889634f;
        gemm_tile<bf16, float>(in_q, WqT, bq, scale, Qw, 4096, 2048, 1024,
                               (bid >> 4) * 128, (bid & 15) * 128, false, As, Bs);
    } else if (bid < 640) {
        int b2 = bid - 512;
        gemm_tile64<bf16, false, float>(in_k, WkT, bk, 1.0f, Kw, 4096, 256, 1024,
                                        (b2 >> 1) * 64, (b2 & 1) * 128,
                                        (bf16*)As, (bf16*)Bs);
    } else {
        int b2 = bid - 640;
        gemm_tile64<bf16, true, float>(in_v, WvT, bv, 1.0f, VwT, 4096, 256, 1024,
                                       (b2 >> 1) * 64, (b2 & 1) * 128,
                                       (bf16*)As, (bf16*)Bs);
    }
}

// ---------------- output projection (64x128 tiles, 512 blocks) --------------
__global__ __launch_bounds__(512, 4) void proj_o(
    const bf16* __restrict__ Cw, const bf16* __restrict__ WoT,
    const float* __restrict__ bo, float* __restrict__ out)
{
    __shared__ bf16 As[2][64 * 64];
    __shared__ bf16 Bs[2][128 * 64];
    gemm_tile64<float, false, bf16>(Cw, WoT, bo, 1.0f, out, 4096, 1024, 2048,
                                    (blockIdx.x >> 3) * 64, (blockIdx.x & 7) * 128,
                                    (bf16*)As, (bf16*)Bs);
}

// ---------------- flash attention (causal, GQA), 32x32 MFMA, pipelined ------
// ROUND-7 WINNER, unchanged. grid (16,16,2); 256 thr = 4 waves =
// 2 q-subtiles(32 rows) x 2 kv-halves(32 keys). Paired passes: qt = 31-bx
// then bx (uniform 33 iters/block). LDS 64 KB flat: Kb0/Kb1/Vb0/Vb1 8K each.
// T15 pipeline, ONE barrier/iter; K staged 1 tile ahead of V.
__global__ __launch_bounds__(256, 2) void attn_fused(
    const bf16* __restrict__ Q,    // [B*L, H*128], pre-scaled
    const bf16* __restrict__ Kp,   // [B*L, G*128]
    const bf16* __restrict__ VT,   // [G*128, B*L]
    bf16* __restrict__ ctx)        // [B*L, H*128]
{
    __shared__ bf16 smem[32768];   // 64 KB

    const int tid  = threadIdx.x;
    const int wave = tid >> 6;
    const int lane = tid & 63;
    const int hi   = lane >> 5;
    const int l31  = lane & 31;
    const int s7   = l31 & 7;
    const int wq   = wave >> 1;    // q sub-tile (rows wq*32..+32 of block tile)
    const int kvw  = wave & 1;     // kv half (keys kvw*32..+32 of each kt tile)

    const int h = blockIdx.y;
    const int b = blockIdx.z;
    const int g = h >> 3;

    const bf16* kgbase = Kp + (size_t)(b * Lz) * (Gz * DQKz) + g * DQKz;
    const bf16* vgbase = VT + (size_t)(g * DVz) * (Bz * Lz) + b * Lz;

    // staging offsets (kt-invariant). LDS chunk ch of row r holds global
    // chunk ch^(r&7) (involution; read side applies the same XOR).
    int kgo[4], vgo[4], ldso[4];
    #pragma unroll
    for (int s = 0; s < 4; ++s) {
        int i = s * 256 + tid;
        ldso[s] = i * 8;
        int key = i >> 4, ck = (i & 15) ^ (key & 7);
        kgo[s] = key * (Gz * DQKz) + ck * 8;
        int dvr = i >> 3, cv = (i & 7) ^ (dvr & 7);
        vgo[s] = dvr * (Bz * Lz) + cv * 8;
    }
    auto stage_K = [&](int kt, int buf) {
        const bf16* kb = kgbase + (size_t)(kt * 64) * (Gz * DQKz);
        #pragma unroll
        for (int s = 0; s < 4; ++s)
            async_copy16(kb + kgo[s], smem + buf * 8192 + ldso[s]);
    };
    auto stage_V = [&](int kt, int buf) {
        const bf16* vb = vgbase + kt * 64;
        #pragma unroll
        for (int s = 0; s < 4; ++s)
            async_copy16(vb + vgo[s], smem + 16384 + buf * 8192 + ldso[s]);
    };

    // LDS read offsets (kt-invariant). K A-frag: row=kvw*32+l31, d-chunk
    // 2ks+hi; V A-frag: row=dt*32+l31, key-chunk kvw*4+kss*2+hi.
    int koff[8];
    #pragma unroll
    for (int ks = 0; ks < 8; ++ks)
        koff[ks] = ((kvw * 32 + l31) * 16 + ((ks * 2 + hi) ^ s7)) * 8;
    int voff[4][2];
    #pragma unroll
    for (int dt = 0; dt < 4; ++dt)
        #pragma unroll
        for (int kss = 0; kss < 2; ++kss)
            voff[dt][kss] = ((dt * 32 + l31) * 8
                             + ((kvw * 4 + kss * 2 + hi) ^ s7)) * 8;

    for (int pass = 0; pass < 2; ++pass) {
        const int qt  = pass == 0 ? (31 - (int)blockIdx.x) : (int)blockIdx.x;
        const int q0  = qt * 64;
        const int nkt = qt + 1;
        const int qrow = q0 + wq * 32 + l31;

        // Q fragments in registers: B-operand, qrow = lane col, 8 k-steps
        bf16x8 qf[8];
        {
            const bf16* qbase = Q + (size_t)(b * Lz + qrow) * (Hz * DQKz) + h * DQKz;
            #pragma unroll
            for (int s = 0; s < 8; ++s)
                qf[s] = *(const bf16x8*)(qbase + s * 16 + hi * 8);
        }

        // O^T dv-tiles: dv = dt*32 + crow, col = qrow. NAMED regs (rule #20).
        f32x16 oacc0 = {}, oacc1 = {}, oacc2 = {}, oacc3 = {};
        f32x16 saccA = {}, saccB = {};
        float lsum = 0.0f;

        if (pass) __syncthreads();   // protect epilogue-LDS reads of pass 0
        stage_K(0, 0);
        stage_V(0, 0);
        if (nkt > 1) stage_K(1, 1);
        __syncthreads();             // K(0), V(0), K(1) landed

        // QK(0) -> saccA
        {
            f32x16 s = {};
            #pragma unroll
            for (int ks = 0; ks < 8; ++ks) {
                bf16x8 kf = *(const bf16x8*)(smem + koff[ks]);
                s = MFMA32(kf, qf[ks], s);
            }
            saccA = s;
        }

        // pipelined iteration: scur = S(t); computes snxt = S(t+1).
        auto iter_body = [&](int t, f32x16& scur, f32x16& snxt) {
            __syncthreads();   // t=0: fences QK(0) readers of Kb0 before
                               // staging K(2); t>0: drains K(t+1), V(t).
            if (t + 2 < nkt) stage_K(t + 2, t & 1);
            if (t + 1 < nkt) stage_V(t + 1, (t + 1) & 1);

            // QK(t+1) -> snxt (independent of SM(t) below -> overlap)
            if (t + 1 < nkt) {
                const bf16* kc = smem + ((t + 1) & 1) * 8192;
                f32x16 s = {};
                #pragma unroll
                for (int ks = 0; ks < 8; ++ks) {
                    bf16x8 kf = *(const bf16x8*)(kc + koff[ks]);
                    s = MFMA32(kf, qf[ks], s);
                }
                snxt = s;
            }

            // SM(t): P = exp2(S - 8); mask only the diagonal tile.
            float pv[16];
            if (t == nkt - 1) {
                #pragma unroll
                for (int r = 0; r < 16; ++r) {
                    int key = kvw * 32 + (r & 3) + 8 * (r >> 2) + 4 * hi;
                    pv[r] = (key > wq * 32 + l31) ? 0.0f
                                                  : exp2f(scur[r] - 8.0f);
                }
            } else {
                #pragma unroll
                for (int r = 0; r < 16; ++r)
                    pv[r] = exp2f(scur[r] - 8.0f);
            }
            lsum += ((pv[0] + pv[1]) + (pv[2] + pv[3]))
                  + ((pv[4] + pv[5]) + (pv[6] + pv[7]))
                  + ((pv[8] + pv[9]) + (pv[10] + pv[11]))
                  + ((pv[12] + pv[13]) + (pv[14] + pv[15]));

            // P -> PV B-operand in registers (T12): pack pairs, swap halves.
            unsigned c0 = cvt_pk_bf16(pv[0],  pv[1]);
            unsigned c1 = cvt_pk_bf16(pv[2],  pv[3]);
            unsigned c2 = cvt_pk_bf16(pv[4],  pv[5]);
            unsigned c3 = cvt_pk_bf16(pv[6],  pv[7]);
            unsigned c4 = cvt_pk_bf16(pv[8],  pv[9]);
            unsigned c5 = cvt_pk_bf16(pv[10], pv[11]);
            unsigned c6 = cvt_pk_bf16(pv[12], pv[13]);
            unsigned c7 = cvt_pk_bf16(pv[14], pv[15]);
            asm("v_permlane32_swap_b32 %0, %1" : "+v"(c0), "+v"(c2));
            asm("v_permlane32_swap_b32 %0, %1" : "+v"(c1), "+v"(c3));
            asm("v_permlane32_swap_b32 %0, %1" : "+v"(c4), "+v"(c6));
            asm("v_permlane32_swap_b32 %0, %1" : "+v"(c5), "+v"(c7));
            union { unsigned u[4]; bf16x8 v; } p0 = {{c0, c1, c2, c3}};
            union { unsigned u[4]; bf16x8 v; } p1 = {{c4, c5, c6, c7}};

            // PV(t): O^T += V^T P^T : 4 dv-tiles x 2 k-steps
            const bf16* vcur = smem + 16384 + (t & 1) * 8192;
            __builtin_amdgcn_s_setprio(1);
            {
                bf16x8 vf;
                vf = *(const bf16x8*)(vcur + voff[0][0]); oacc0 = MFMA32(vf, p0.v, oacc0);
                vf = *(const bf16x8*)(vcur + voff[0][1]); oacc0 = MFMA32(vf, p1.v, oacc0);
                vf = *(const bf16x8*)(vcur + voff[1][0]); oacc1 = MFMA32(vf, p0.v, oacc1);
                vf = *(const bf16x8*)(vcur + voff[1][1]); oacc1 = MFMA32(vf, p1.v, oacc1);
                vf = *(const bf16x8*)(vcur + voff[2][0]); oacc2 = MFMA32(vf, p0.v, oacc2);
                vf = *(const bf16x8*)(vcur + voff[2][1]); oacc2 = MFMA32(vf, p1.v, oacc2);
                vf = *(const bf16x8*)(vcur + voff[3][0]); oacc3 = MFMA32(vf, p0.v, oacc3);
                vf = *(const bf16x8*)(vcur + voff[3][1]); oacc3 = MFMA32(vf, p1.v, oacc3);
            }
            __builtin_amdgcn_s_setprio(0);
        };

        int t = 0;
        for (; t + 2 <= nkt; t += 2) {
            iter_body(t,     saccA, saccB);
            iter_body(t + 1, saccB, saccA);
        }
        if (nkt & 1) iter_body(nkt - 1, saccA, saccB);

        // in-wave: combine hi halves (same qrow)
        lsum += __shfl_xor(lsum, 32);

        // cross-wave (kv-half) combine via LDS; stride 20 = conflict-free.
        // Flat over smem: E0 [0,5120), E1 [5120,10240), LS [10240,) floats.
        float* SM = (float*)smem;
        float* E0 = SM;
        float* E1 = SM + 5120;
        float* LS = SM + 10240;
        __syncthreads();                   // all waves done with K/V tiles

        auto store_partial = [&](f32x16 v, float* E) {
            #pragma unroll
            for (int j = 0; j < 4; ++j) {
                f32x4 v4 = { v[4 * j], v[4 * j + 1], v[4 * j + 2], v[4 * j + 3] };
                *(f32x4*)&E[(wave * 64 + lane) * 20 + 4 * j] = v4;
            }
        };
        if (kvw == 0) { store_partial(oacc2, E0); store_partial(oacc3, E1); }
        else          { store_partial(oacc0, E0); store_partial(oacc1, E1); }
        if (lane < 32) LS[wave * 32 + lane] = lsum;
        __syncthreads();
        lsum += LS[(wave ^ 1) * 32 + l31];
        const float inv = 1.0f / lsum;

        // finalize kept tiles: own partial + partner's, normalize, store.
        bf16* cbase = ctx + (size_t)(b * Lz + qrow) * (Hz * DVz) + h * DVz;
        auto finalize = [&](f32x16 v, float* E, int dt) {
            #pragma unroll
            for (int j = 0; j < 4; ++j) {
                f32x4 p4 = *(const f32x4*)&E[((wave ^ 1) * 64 + lane) * 20 + 4 * j];
                bf16x4 o4;
                #pragma unroll
                for (int r = 0; r < 4; ++r)
                    o4[r] = (bf16)((v[4 * j + r] + p4[r]) * inv);
                *(bf16x4*)&cbase[dt * 32 + j * 8 + hi * 4] = o4;
            }
        };
        if (kvw == 0) { finalize(oacc0, E0, 0); finalize(oacc1, E1, 1); }
        else          { finalize(oacc2, E0, 2); finalize(oacc3, E1, 3); }
    }
}

// ---------------------------------------------------------------------------
extern "C" void kernel_launch(void* const* d_in, const int* in_sizes, int n_in,
                              void* d_out, int out_size, void* d_ws, size_t ws_size,
                              hipStream_t stream)
{
    (void)in_sizes; (void)n_in; (void)out_size; (void)ws_size;

    const float* in_q = (const float*)d_in[0];
    const float* in_k = (const float*)d_in[1];
    const float* in_v = (const float*)d_in[2];
    const float* Wq   = (const float*)d_in[3];
    const float* bq   = (const float*)d_in[4];
    const float* Wk   = (const float*)d_in[5];
    const float* bk   = (const float*)d_in[6];
    const float* Wv   = (const float*)d_in[7];
    const float* bv   = (const float*)d_in[8];
    const float* Wo   = (const float*)d_in[9];
    const float* bo   = (const float*)d_in[10];
    const float* qsc  = (const float*)d_in[11];
    float* out = (float*)d_out;

    const int M = Bz * Lz;                       // 4096
    const int NQ = Hz * DQKz;                    // 2048
    const int NKV = Gz * DQKz;                   // 256

    // workspace (bf16 elems): transposed weights + intermediates (~45 MB)
    bf16* WqT = (bf16*)d_ws;                     // 2M
    bf16* WkT = WqT + (size_t)NQ * Dz;           // 0.25M
    bf16* WvT = WkT + (size_t)NKV * Dz;          // 0.25M
    bf16* WoT = WvT + (size_t)NKV * Dz;          // 2M
    bf16* Qw  = WoT + (size_t)Dz * NQ;           // 8M
    bf16* Kw  = Qw  + (size_t)M * NQ;            // 1M
    bf16* VwT = Kw  + (size_t)M * NKV;           // 1M
    bf16* Cw  = VwT + (size_t)NKV * M;           // 8M

    // 1) prep: weight transposes only (input cvt fused into proj_qkv)
    prep<<<dim3(4608), dim3(256), 0, stream>>>(
        Wq, Wk, Wv, Wo, WqT, WkT, WvT, WoT);

    // 2) Q/K/V projections from fp32 inputs (768 blocks = 3/CU uniform)
    proj_qkv<<<dim3(768), dim3(512), 0, stream>>>(
        in_q, in_k, in_v, WqT, WkT, WvT, bq, bk, bv, qsc, Qw, Kw, VwT);

    // 3) attention (pair-balanced grid; round-7 winner)
    attn_fused<<<dim3(16, Hz, Bz), dim3(256), 0, stream>>>(Qw, Kw, VwT, Cw);

    // 4) output projection -> fp32 out (64x128 tiles, 512 blocks)
    proj_o<<<dim3(512), dim3(512), 0, stream>>>(Cw, WoT, bo, out);
}

// Round 13
// 236.711 us; speedup vs baseline: 1.0326x; 1.0326x over previous
//
#include <hip/hip_runtime.h>

// ---------------------------------------------------------------------------
// Fused GQA attention: B=2, L=2048, D=1024, H=16, G=2, HPG=8, DQK=DV=128.
// Inputs fp32, OUTPUT fp32. bf16 MFMA compute, fp32 accumulation.
//
// attn: 32x32x16 MFMA, in-register P (T12), T15 QK||SM pipeline, 64 KB LDS,
// launch_bounds(256,2) -- round-7 winner (round-8: 3 waves/EU spills accs).
//
// ROUND-13: (1) T1 XCD-aware block swizzle on Q-proj and proj_o grids
// (bijective: 512%8==0); panel reuse becomes L2-local across the 8
// non-coherent XCD L2s. (2) attn exp2 domain shift dropped (exp2(S) ==
// 2^8 * exp2(S-8); factor cancels in O=sum(PV)/sum(P); bf16 mantissas
// identical) -- saves 16 v_sub/iter. All else = measured round-12 state.
// ---------------------------------------------------------------------------

typedef __bf16 bf16;
typedef __bf16 bf16x8 __attribute__((ext_vector_type(8)));
typedef __bf16 bf16x4 __attribute__((ext_vector_type(4)));
typedef float f32x4 __attribute__((ext_vector_type(4)));
typedef float f32x16 __attribute__((ext_vector_type(16)));
typedef float float4v __attribute__((ext_vector_type(4)));

#define MFMA_BF16(a, b, c) __builtin_amdgcn_mfma_f32_16x16x32_bf16((a), (b), (c), 0, 0, 0)
#define MFMA32(a, b, c)    __builtin_amdgcn_mfma_f32_32x32x16_bf16((a), (b), (c), 0, 0, 0)

static constexpr int Bz = 2, Lz = 2048, Dz = 1024;
static constexpr int Hz = 16, Gz = 2;
static constexpr int DQKz = 128, DVz = 128;

__device__ __forceinline__ void async_copy16(const bf16* g, bf16* l) {
    __builtin_amdgcn_global_load_lds(
        (const __attribute__((address_space(1))) unsigned int*)g,
        (__attribute__((address_space(3))) unsigned int*)l, 16, 0, 0);
}

__device__ __forceinline__ unsigned cvt_pk_bf16(float lo, float hi) {
    unsigned r;
    asm("v_cvt_pk_bf16_f32 %0, %1, %2" : "=v"(r) : "v"(lo), "v"(hi));
    return r;
}

__device__ __forceinline__ bf16x8 cvt8(float4v a, float4v b) {
    bf16x8 o;
    #pragma unroll
    for (int j = 0; j < 4; ++j) { o[j] = (bf16)a[j]; o[j + 4] = (bf16)b[j]; }
    return o;
}

// ---------------- prep: weight transposes only ------------------------------
// grid: 4608 blocks x 256 thr; 32x32 tiles: Wq 2048, Wk 256, Wv 256, Wo 2048
__global__ __launch_bounds__(256) void prep(
    const float* __restrict__ Wq, const float* __restrict__ Wk,
    const float* __restrict__ Wv, const float* __restrict__ Wo,
    bf16* __restrict__ WqT, bf16* __restrict__ WkT,
    bf16* __restrict__ WvT, bf16* __restrict__ WoT)
{
    int bid = blockIdx.x;
    const float* W; bf16* WT; int K, N;
    if (bid < 2048)      { W = Wq; WT = WqT; K = 1024; N = 2048; }
    else if (bid < 2304) { W = Wk; WT = WkT; K = 1024; N = 256;  bid -= 2048; }
    else if (bid < 2560) { W = Wv; WT = WvT; K = 1024; N = 256;  bid -= 2304; }
    else                 { W = Wo; WT = WoT; K = 2048; N = 1024; bid -= 2560; }
    int tiles_n = N >> 5;
    int n0 = (bid % tiles_n) * 32, k0 = (bid / tiles_n) * 32;

    __shared__ bf16 t[32][33];
    int tx = threadIdx.x & 31, ty = threadIdx.x >> 5;
    #pragma unroll
    for (int i = 0; i < 4; ++i)
        t[ty + i * 8][tx] = (bf16)W[(size_t)(k0 + ty + i * 8) * N + n0 + tx];
    __syncthreads();
    #pragma unroll
    for (int i = 0; i < 4; ++i)
        WT[(size_t)(n0 + ty + i * 8) * K + k0 + tx] = t[tx][ty + i * 8];
}

// ---------------- pipelined GEMM body: 128x128 tile, BK64, 512 thr ----------
// 8 waves as 2(m) x 4(n); wave-tile 64x32. Double-buffered LDS, single
// barrier per k-iter. F32A: A is fp32, reg-staged (load early, cvt+ds_write
// after the MFMA block -- T14 split; barrier drains vmcnt+lgkmcnt).
template <typename TC, typename TA>
__device__ __forceinline__ void gemm_tile(
    const TA* __restrict__ A, const bf16* __restrict__ BT,
    const float* __restrict__ bias, float scale, TC* __restrict__ C,
    int M, int N, int K, int m0, int n0, bool trans_out,
    bf16 (&As)[2][128 * 64], bf16 (&Bs)[2][128 * 64])
{
    constexpr bool F32A = sizeof(TA) == 4;
    const int tid  = threadIdx.x;        // 512
    const int wave = tid >> 6;
    const int lane = tid & 63;
    const int quad = lane >> 4;
    const int l16  = lane & 15;
    const int sw   = l16 & 7;
    const int wm = wave >> 2, wn = wave & 3;

    f32x4 acc[4][2] = {};

    auto stageA_async = [&](int k0, int buf) {   // TA == bf16 path
        #pragma unroll
        for (int s = 0; s < 2; ++s) {
            int i = s * 512 + tid;
            int row = i >> 3, c = (i & 7) ^ (row & 7);
            async_copy16((const bf16*)A + (size_t)(m0 + row) * K + k0 + c * 8,
                         &As[buf][i * 8]);
        }
    };
    auto loadA = [&](int k0, float4v (&ra)[2][2]) {  // TA == float path
        #pragma unroll
        for (int s = 0; s < 2; ++s) {
            int i = s * 512 + tid;
            int row = i >> 3, c = (i & 7) ^ (row & 7);
            const float* src = (const float*)A + (size_t)(m0 + row) * K + k0 + c * 8;
            ra[s][0] = *(const float4v*)src;
            ra[s][1] = *(const float4v*)(src + 4);
        }
    };
    auto writeA = [&](int buf, float4v (&ra)[2][2]) {
        #pragma unroll
        for (int s = 0; s < 2; ++s) {
            int i = s * 512 + tid;
            *(bf16x8*)(&As[buf][i * 8]) = cvt8(ra[s][0], ra[s][1]);
        }
    };
    auto stageB = [&](int k0, int buf) {
        #pragma unroll
        for (int s = 0; s < 2; ++s) {
            int i = s * 512 + tid;
            int row = i >> 3, c = (i & 7) ^ (row & 7);
            async_copy16(BT + (size_t)(n0 + row) * K + k0 + c * 8, &Bs[buf][i * 8]);
        }
    };

    // prologue
    float4v ra[2][2];
    if constexpr (F32A) { loadA(0, ra); stageB(0, 0); writeA(0, ra); }
    else                { stageA_async(0, 0); stageB(0, 0); }

    int cur = 0;
    for (int k0 = 0; k0 < K; k0 += 64) {
        __syncthreads();                    // drains async loads + ds_writes
        const bool hav = (k0 + 64 < K);
        float4v rn[2][2];
        if (hav) {
            if constexpr (F32A) loadA(k0 + 64, rn);   // issue early (T14)
            else                stageA_async(k0 + 64, cur ^ 1);
            stageB(k0 + 64, cur ^ 1);
        }

        #pragma unroll
        for (int ks = 0; ks < 2; ++ks) {
            bf16x8 af[4], bfv[2];
            #pragma unroll
            for (int mt = 0; mt < 4; ++mt)
                af[mt] = *(const bf16x8*)(&As[cur][((wm * 64 + mt * 16 + l16) * 8
                                                    + ((ks * 4 + quad) ^ sw)) * 8]);
            #pragma unroll
            for (int nt = 0; nt < 2; ++nt)
                bfv[nt] = *(const bf16x8*)(&Bs[cur][((wn * 32 + nt * 16 + l16) * 8
                                                     + ((ks * 4 + quad) ^ sw)) * 8]);
            #pragma unroll
            for (int mt = 0; mt < 4; ++mt)
                #pragma unroll
                for (int nt = 0; nt < 2; ++nt)
                    acc[mt][nt] = MFMA_BF16(af[mt], bfv[nt], acc[mt][nt]);
        }

        if constexpr (F32A) { if (hav) writeA(cur ^ 1, rn); }  // write late
        cur ^= 1;
    }

    #pragma unroll
    for (int nt = 0; nt < 2; ++nt) {
        int col = n0 + wn * 32 + nt * 16 + l16;
        float bv = bias[col];
        #pragma unroll
        for (int mt = 0; mt < 4; ++mt) {
            int row = m0 + wm * 64 + mt * 16 + quad * 4;
            if (trans_out) {
                struct V4 { TC v[4]; } o;
                #pragma unroll
                for (int r = 0; r < 4; ++r)
                    o.v[r] = (TC)((acc[mt][nt][r] + bv) * scale);
                *(V4*)(&C[(size_t)col * M + row]) = o;
            } else {
                #pragma unroll
                for (int r = 0; r < 4; ++r)
                    C[(size_t)(row + r) * N + col] =
                        (TC)((acc[mt][nt][r] + bv) * scale);
            }
        }
    }
}

// ---------------- GEMM body 64x128 tile, BK64, 512 thr ----------------------
// 8 waves as 2(m) x 4(n); wave-tile 32x32 (acc[2][2]). As = 2x64x64,
// Bs = 2x128x64 (raw pointers; may alias a larger allocation).
template <typename TC, bool TRANS, typename TA>
__device__ __forceinline__ void gemm_tile64(
    const TA* __restrict__ A, const bf16* __restrict__ BT,
    const float* __restrict__ bias, float scale, TC* __restrict__ C,
    int M, int N, int K, int m0, int n0, bf16* As, bf16* Bs)
{
    constexpr bool F32A = sizeof(TA) == 4;
    const int tid  = threadIdx.x;        // 512
    const int wave = tid >> 6;
    const int lane = tid & 63;
    const int quad = lane >> 4;
    const int l16  = lane & 15;
    const int sw   = l16 & 7;
    const int wm = wave >> 2, wn = wave & 3;   // 2m x 4n

    f32x4 acc[2][2] = {};

    auto stageA_async = [&](int k0, int buf) {
        int i = tid;                       // 64x64 = 512 x 16B, 1 round
        int row = i >> 3, c = (i & 7) ^ (row & 7);
        async_copy16((const bf16*)A + (size_t)(m0 + row) * K + k0 + c * 8,
                     As + buf * 4096 + i * 8);
    };
    auto loadA = [&](int k0, float4v (&ra)[2]) {
        int i = tid;
        int row = i >> 3, c = (i & 7) ^ (row & 7);
        const float* src = (const float*)A + (size_t)(m0 + row) * K + k0 + c * 8;
        ra[0] = *(const float4v*)src;
        ra[1] = *(const float4v*)(src + 4);
    };
    auto writeA = [&](int buf, float4v (&ra)[2]) {
        *(bf16x8*)(As + buf * 4096 + tid * 8) = cvt8(ra[0], ra[1]);
    };
    auto stageB = [&](int k0, int buf) {
        #pragma unroll
        for (int s = 0; s < 2; ++s) {          // 128x64 = 2 rounds
            int i = s * 512 + tid;
            int row = i >> 3, c = (i & 7) ^ (row & 7);
            async_copy16(BT + (size_t)(n0 + row) * K + k0 + c * 8,
                         Bs + buf * 8192 + i * 8);
        }
    };

    float4v ra[2];
    if constexpr (F32A) { loadA(0, ra); stageB(0, 0); writeA(0, ra); }
    else                { stageA_async(0, 0); stageB(0, 0); }

    int cur = 0;
    for (int k0 = 0; k0 < K; k0 += 64) {
        __syncthreads();                    // drains async loads + ds_writes
        const bool hav = (k0 + 64 < K);
        float4v rn[2];
        if (hav) {
            if constexpr (F32A) loadA(k0 + 64, rn);
            else                stageA_async(k0 + 64, cur ^ 1);
            stageB(k0 + 64, cur ^ 1);
        }

        #pragma unroll
        for (int ks = 0; ks < 2; ++ks) {
            bf16x8 af[2], bfv[2];
            #pragma unroll
            for (int mt = 0; mt < 2; ++mt)
                af[mt] = *(const bf16x8*)(As + cur * 4096
                           + ((wm * 32 + mt * 16 + l16) * 8
                              + ((ks * 4 + quad) ^ sw)) * 8);
            #pragma unroll
            for (int nt = 0; nt < 2; ++nt)
                bfv[nt] = *(const bf16x8*)(Bs + cur * 8192
                            + ((wn * 32 + nt * 16 + l16) * 8
                               + ((ks * 4 + quad) ^ sw)) * 8);
            #pragma unroll
            for (int mt = 0; mt < 2; ++mt)
                #pragma unroll
                for (int nt = 0; nt < 2; ++nt)
                    acc[mt][nt] = MFMA_BF16(af[mt], bfv[nt], acc[mt][nt]);
        }

        if constexpr (F32A) { if (hav) writeA(cur ^ 1, rn); }
        cur ^= 1;
    }

    #pragma unroll
    for (int nt = 0; nt < 2; ++nt) {
        int col = n0 + wn * 32 + nt * 16 + l16;
        float bv = bias[col];
        #pragma unroll
        for (int mt = 0; mt < 2; ++mt) {
            int row = m0 + wm * 32 + mt * 16 + quad * 4;
            if constexpr (TRANS) {
                struct V4 { TC v[4]; } o;
                #pragma unroll
                for (int r = 0; r < 4; ++r)
                    o.v[r] = (TC)((acc[mt][nt][r] + bv) * scale);
                *(V4*)(&C[(size_t)col * M + row]) = o;
            } else {
                #pragma unroll
                for (int r = 0; r < 4; ++r)
                    C[(size_t)(row + r) * N + col] =
                        (TC)((acc[mt][nt][r] + bv) * scale);
            }
        }
    }
}

// ---------------- Q+K+V projections (read fp32 inputs directly) -------------
// grid 768 = 3 blocks/CU uniform: [0,512) Q 128x128 (T1 XCD-swizzled);
// [512,640) K 64x128; [640,768) V 64x128 transposed-out.
__global__ __launch_bounds__(512, 4) void proj_qkv(
    const float* __restrict__ in_q, const float* __restrict__ in_k,
    const float* __restrict__ in_v, const bf16* __restrict__ WqT,
    const bf16* __restrict__ WkT, const bf16* __restrict__ WvT,
    const float* __restrict__ bq, const float* __restrict__ bk,
    const float* __restrict__ bv, const float* __restrict__ qsc,
    bf16* __restrict__ Qw, bf16* __restrict__ Kw, bf16* __restrict__ VwT)
{
    __shared__ bf16 As[2][128 * 64];
    __shared__ bf16 Bs[2][128 * 64];
    int bid = blockIdx.x;
    if (bid < 512) {
        // T1: bijective XCD chunk swizzle (512 % 8 == 0). Each XCD gets 64
        // contiguous tiles (4 m x 16 n) -> A/B panel reuse is L2-local.
        int swz = ((bid & 7) << 6) | (bid >> 3);
        // scale = qsc / sqrt(128) * log2(e)  (exp2-domain softmax)
        float scale = qsc[0] * 0.08838834764831845f * 1.4426950408889634f;
        gemm_tile<bf16, float>(in_q, WqT, bq, scale, Qw, 4096, 2048, 1024,
                               (swz >> 4) * 128, (swz & 15) * 128, false, As, Bs);
    } else if (bid < 640) {
        int b2 = bid - 512;
        gemm_tile64<bf16, false, float>(in_k, WkT, bk, 1.0f, Kw, 4096, 256, 1024,
                                        (b2 >> 1) * 64, (b2 & 1) * 128,
                                        (bf16*)As, (bf16*)Bs);
    } else {
        int b2 = bid - 640;
        gemm_tile64<bf16, true, float>(in_v, WvT, bv, 1.0f, VwT, 4096, 256, 1024,
                                       (b2 >> 1) * 64, (b2 & 1) * 128,
                                       (bf16*)As, (bf16*)Bs);
    }
}

// ---------------- output projection (64x128 tiles, 512 blocks, T1 swz) ------
__global__ __launch_bounds__(512, 4) void proj_o(
    const bf16* __restrict__ Cw, const bf16* __restrict__ WoT,
    const float* __restrict__ bo, float* __restrict__ out)
{
    __shared__ bf16 As[2][64 * 64];
    __shared__ bf16 Bs[2][128 * 64];
    int bid = blockIdx.x;
    int swz = ((bid & 7) << 6) | (bid >> 3);   // bijective (512 % 8 == 0)
    gemm_tile64<float, false, bf16>(Cw, WoT, bo, 1.0f, out, 4096, 1024, 2048,
                                    (swz >> 3) * 64, (swz & 7) * 128,
                                    (bf16*)As, (bf16*)Bs);
}

// ---------------- flash attention (causal, GQA), 32x32 MFMA, pipelined ------
// ROUND-7 structure. grid (16,16,2); 256 thr = 4 waves = 2 q-subtiles x
// 2 kv-halves. Paired passes (uniform 33 iters/block). LDS 64 KB flat.
// T15 pipeline, ONE barrier/iter; K staged 1 tile ahead of V.
// ROUND-13: exp2(S) directly (the -8 shift cancels in O = sum(PV)/sum(P)).
__global__ __launch_bounds__(256, 2) void attn_fused(
    const bf16* __restrict__ Q,    // [B*L, H*128], pre-scaled
    const bf16* __restrict__ Kp,   // [B*L, G*128]
    const bf16* __restrict__ VT,   // [G*128, B*L]
    bf16* __restrict__ ctx)        // [B*L, H*128]
{
    __shared__ bf16 smem[32768];   // 64 KB

    const int tid  = threadIdx.x;
    const int wave = tid >> 6;
    const int lane = tid & 63;
    const int hi   = lane >> 5;
    const int l31  = lane & 31;
    const int s7   = l31 & 7;
    const int wq   = wave >> 1;    // q sub-tile (rows wq*32..+32 of block tile)
    const int kvw  = wave & 1;     // kv half (keys kvw*32..+32 of each kt tile)

    const int h = blockIdx.y;
    const int b = blockIdx.z;
    const int g = h >> 3;

    const bf16* kgbase = Kp + (size_t)(b * Lz) * (Gz * DQKz) + g * DQKz;
    const bf16* vgbase = VT + (size_t)(g * DVz) * (Bz * Lz) + b * Lz;

    // staging offsets (kt-invariant). LDS chunk ch of row r holds global
    // chunk ch^(r&7) (involution; read side applies the same XOR).
    int kgo[4], vgo[4], ldso[4];
    #pragma unroll
    for (int s = 0; s < 4; ++s) {
        int i = s * 256 + tid;
        ldso[s] = i * 8;
        int key = i >> 4, ck = (i & 15) ^ (key & 7);
        kgo[s] = key * (Gz * DQKz) + ck * 8;
        int dvr = i >> 3, cv = (i & 7) ^ (dvr & 7);
        vgo[s] = dvr * (Bz * Lz) + cv * 8;
    }
    auto stage_K = [&](int kt, int buf) {
        const bf16* kb = kgbase + (size_t)(kt * 64) * (Gz * DQKz);
        #pragma unroll
        for (int s = 0; s < 4; ++s)
            async_copy16(kb + kgo[s], smem + buf * 8192 + ldso[s]);
    };
    auto stage_V = [&](int kt, int buf) {
        const bf16* vb = vgbase + kt * 64;
        #pragma unroll
        for (int s = 0; s < 4; ++s)
            async_copy16(vb + vgo[s], smem + 16384 + buf * 8192 + ldso[s]);
    };

    // LDS read offsets (kt-invariant). K A-frag: row=kvw*32+l31, d-chunk
    // 2ks+hi; V A-frag: row=dt*32+l31, key-chunk kvw*4+kss*2+hi.
    int koff[8];
    #pragma unroll
    for (int ks = 0; ks < 8; ++ks)
        koff[ks] = ((kvw * 32 + l31) * 16 + ((ks * 2 + hi) ^ s7)) * 8;
    int voff[4][2];
    #pragma unroll
    for (int dt = 0; dt < 4; ++dt)
        #pragma unroll
        for (int kss = 0; kss < 2; ++kss)
            voff[dt][kss] = ((dt * 32 + l31) * 8
                             + ((kvw * 4 + kss * 2 + hi) ^ s7)) * 8;

    for (int pass = 0; pass < 2; ++pass) {
        const int qt  = pass == 0 ? (31 - (int)blockIdx.x) : (int)blockIdx.x;
        const int q0  = qt * 64;
        const int nkt = qt + 1;
        const int qrow = q0 + wq * 32 + l31;

        // Q fragments in registers: B-operand, qrow = lane col, 8 k-steps
        bf16x8 qf[8];
        {
            const bf16* qbase = Q + (size_t)(b * Lz + qrow) * (Hz * DQKz) + h * DQKz;
            #pragma unroll
            for (int s = 0; s < 8; ++s)
                qf[s] = *(const bf16x8*)(qbase + s * 16 + hi * 8);
        }

        // O^T dv-tiles: dv = dt*32 + crow, col = qrow. NAMED regs (rule #20).
        f32x16 oacc0 = {}, oacc1 = {}, oacc2 = {}, oacc3 = {};
        f32x16 saccA = {}, saccB = {};
        float lsum = 0.0f;

        if (pass) __syncthreads();   // protect epilogue-LDS reads of pass 0
        stage_K(0, 0);
        stage_V(0, 0);
        if (nkt > 1) stage_K(1, 1);
        __syncthreads();             // K(0), V(0), K(1) landed

        // QK(0) -> saccA
        {
            f32x16 s = {};
            #pragma unroll
            for (int ks = 0; ks < 8; ++ks) {
                bf16x8 kf = *(const bf16x8*)(smem + koff[ks]);
                s = MFMA32(kf, qf[ks], s);
            }
            saccA = s;
        }

        // pipelined iteration: scur = S(t); computes snxt = S(t+1).
        auto iter_body = [&](int t, f32x16& scur, f32x16& snxt) {
            __syncthreads();   // t=0: fences QK(0) readers of Kb0 before
                               // staging K(2); t>0: drains K(t+1), V(t).
            if (t + 2 < nkt) stage_K(t + 2, t & 1);
            if (t + 1 < nkt) stage_V(t + 1, (t + 1) & 1);

            // QK(t+1) -> snxt (independent of SM(t) below -> overlap)
            if (t + 1 < nkt) {
                const bf16* kc = smem + ((t + 1) & 1) * 8192;
                f32x16 s = {};
                #pragma unroll
                for (int ks = 0; ks < 8; ++ks) {
                    bf16x8 kf = *(const bf16x8*)(kc + koff[ks]);
                    s = MFMA32(kf, qf[ks], s);
                }
                snxt = s;
            }

            // SM(t): P = exp2(S); mask only the diagonal tile.
            float pv[16];
            if (t == nkt - 1) {
                #pragma unroll
                for (int r = 0; r < 16; ++r) {
                    int key = kvw * 32 + (r & 3) + 8 * (r >> 2) + 4 * hi;
                    pv[r] = (key > wq * 32 + l31) ? 0.0f
                                                  : exp2f(scur[r]);
                }
            } else {
                #pragma unroll
                for (int r = 0; r < 16; ++r)
                    pv[r] = exp2f(scur[r]);
            }
            lsum += ((pv[0] + pv[1]) + (pv[2] + pv[3]))
                  + ((pv[4] + pv[5]) + (pv[6] + pv[7]))
                  + ((pv[8] + pv[9]) + (pv[10] + pv[11]))
                  + ((pv[12] + pv[13]) + (pv[14] + pv[15]));

            // P -> PV B-operand in registers (T12): pack pairs, swap halves.
            unsigned c0 = cvt_pk_bf16(pv[0],  pv[1]);
            unsigned c1 = cvt_pk_bf16(pv[2],  pv[3]);
            unsigned c2 = cvt_pk_bf16(pv[4],  pv[5]);
            unsigned c3 = cvt_pk_bf16(pv[6],  pv[7]);
            unsigned c4 = cvt_pk_bf16(pv[8],  pv[9]);
            unsigned c5 = cvt_pk_bf16(pv[10], pv[11]);
            unsigned c6 = cvt_pk_bf16(pv[12], pv[13]);
            unsigned c7 = cvt_pk_bf16(pv[14], pv[15]);
            asm("v_permlane32_swap_b32 %0, %1" : "+v"(c0), "+v"(c2));
            asm("v_permlane32_swap_b32 %0, %1" : "+v"(c1), "+v"(c3));
            asm("v_permlane32_swap_b32 %0, %1" : "+v"(c4), "+v"(c6));
            asm("v_permlane32_swap_b32 %0, %1" : "+v"(c5), "+v"(c7));
            union { unsigned u[4]; bf16x8 v; } p0 = {{c0, c1, c2, c3}};
            union { unsigned u[4]; bf16x8 v; } p1 = {{c4, c5, c6, c7}};

            // PV(t): O^T += V^T P^T : 4 dv-tiles x 2 k-steps
            const bf16* vcur = smem + 16384 + (t & 1) * 8192;
            __builtin_amdgcn_s_setprio(1);
            {
                bf16x8 vf;
                vf = *(const bf16x8*)(vcur + voff[0][0]); oacc0 = MFMA32(vf, p0.v, oacc0);
                vf = *(const bf16x8*)(vcur + voff[0][1]); oacc0 = MFMA32(vf, p1.v, oacc0);
                vf = *(const bf16x8*)(vcur + voff[1][0]); oacc1 = MFMA32(vf, p0.v, oacc1);
                vf = *(const bf16x8*)(vcur + voff[1][1]); oacc1 = MFMA32(vf, p1.v, oacc1);
                vf = *(const bf16x8*)(vcur + voff[2][0]); oacc2 = MFMA32(vf, p0.v, oacc2);
                vf = *(const bf16x8*)(vcur + voff[2][1]); oacc2 = MFMA32(vf, p1.v, oacc2);
                vf = *(const bf16x8*)(vcur + voff[3][0]); oacc3 = MFMA32(vf, p0.v, oacc3);
                vf = *(const bf16x8*)(vcur + voff[3][1]); oacc3 = MFMA32(vf, p1.v, oacc3);
            }
            __builtin_amdgcn_s_setprio(0);
        };

        int t = 0;
        for (; t + 2 <= nkt; t += 2) {
            iter_body(t,     saccA, saccB);
            iter_body(t + 1, saccB, saccA);
        }
        if (nkt & 1) iter_body(nkt - 1, saccA, saccB);

        // in-wave: combine hi halves (same qrow)
        lsum += __shfl_xor(lsum, 32);

        // cross-wave (kv-half) combine via LDS; stride 20 = conflict-free.
        // Flat over smem: E0 [0,5120), E1 [5120,10240), LS [10240,) floats.
        float* SM = (float*)smem;
        float* E0 = SM;
        float* E1 = SM + 5120;
        float* LS = SM + 10240;
        __syncthreads();                   // all waves done with K/V tiles

        auto store_partial = [&](f32x16 v, float* E) {
            #pragma unroll
            for (int j = 0; j < 4; ++j) {
                f32x4 v4 = { v[4 * j], v[4 * j + 1], v[4 * j + 2], v[4 * j + 3] };
                *(f32x4*)&E[(wave * 64 + lane) * 20 + 4 * j] = v4;
            }
        };
        if (kvw == 0) { store_partial(oacc2, E0); store_partial(oacc3, E1); }
        else          { store_partial(oacc0, E0); store_partial(oacc1, E1); }
        if (lane < 32) LS[wave * 32 + lane] = lsum;
        __syncthreads();
        lsum += LS[(wave ^ 1) * 32 + l31];
        const float inv = 1.0f / lsum;

        // finalize kept tiles: own partial + partner's, normalize, store.
        bf16* cbase = ctx + (size_t)(b * Lz + qrow) * (Hz * DVz) + h * DVz;
        auto finalize = [&](f32x16 v, float* E, int dt) {
            #pragma unroll
            for (int j = 0; j < 4; ++j) {
                f32x4 p4 = *(const f32x4*)&E[((wave ^ 1) * 64 + lane) * 20 + 4 * j];
                bf16x4 o4;
                #pragma unroll
                for (int r = 0; r < 4; ++r)
                    o4[r] = (bf16)((v[4 * j + r] + p4[r]) * inv);
                *(bf16x4*)&cbase[dt * 32 + j * 8 + hi * 4] = o4;
            }
        };
        if (kvw == 0) { finalize(oacc0, E0, 0); finalize(oacc1, E1, 1); }
        else          { finalize(oacc2, E0, 2); finalize(oacc3, E1, 3); }
    }
}

// ---------------------------------------------------------------------------
extern "C" void kernel_launch(void* const* d_in, const int* in_sizes, int n_in,
                              void* d_out, int out_size, void* d_ws, size_t ws_size,
                              hipStream_t stream)
{
    (void)in_sizes; (void)n_in; (void)out_size; (void)ws_size;

    const float* in_q = (const float*)d_in[0];
    const float* in_k = (const float*)d_in[1];
    const float* in_v = (const float*)d_in[2];
    const float* Wq   = (const float*)d_in[3];
    const float* bq   = (const float*)d_in[4];
    const float* Wk   = (const float*)d_in[5];
    const float* bk   = (const float*)d_in[6];
    const float* Wv   = (const float*)d_in[7];
    const float* bv   = (const float*)d_in[8];
    const float* Wo   = (const float*)d_in[9];
    const float* bo   = (const float*)d_in[10];
    const float* qsc  = (const float*)d_in[11];
    float* out = (float*)d_out;

    const int M = Bz * Lz;                       // 4096
    const int NQ = Hz * DQKz;                    // 2048
    const int NKV = Gz * DQKz;                   // 256

    // workspace (bf16 elems): transposed weights + intermediates (~45 MB)
    bf16* WqT = (bf16*)d_ws;                     // 2M
    bf16* WkT = WqT + (size_t)NQ * Dz;           // 0.25M
    bf16* WvT = WkT + (size_t)NKV * Dz;          // 0.25M
    bf16* WoT = WvT + (size_t)NKV * Dz;          // 2M
    bf16* Qw  = WoT + (size_t)Dz * NQ;           // 8M
    bf16* Kw  = Qw  + (size_t)M * NQ;            // 1M
    bf16* VwT = Kw  + (size_t)M * NKV;           // 1M
    bf16* Cw  = VwT + (size_t)NKV * M;           // 8M

    // 1) prep: weight transposes only (input cvt fused into proj_qkv)
    prep<<<dim3(4608), dim3(256), 0, stream>>>(
        Wq, Wk, Wv, Wo, WqT, WkT, WvT, WoT);

    // 2) Q/K/V projections from fp32 inputs (768 blocks = 3/CU uniform)
    proj_qkv<<<dim3(768), dim3(512), 0, stream>>>(
        in_q, in_k, in_v, WqT, WkT, WvT, bq, bk, bv, qsc, Qw, Kw, VwT);

    // 3) attention (pair-balanced grid; round-7 winner)
    attn_fused<<<dim3(16, Hz, Bz), dim3(256), 0, stream>>>(Qw, Kw, VwT, Cw);

    // 4) output projection -> fp32 out (64x128 tiles, 512 blocks, T1 swz)
    proj_o<<<dim3(512), dim3(512), 0, stream>>>(Cw, WoT, bo, out);
}